// Round 1
// baseline (364.866 us; speedup 1.0000x reference)
//
#include <hip/hip_runtime.h>
#include <math.h>
#include <stddef.h>

// ---------- problem constants ----------
#define B_   8
#define A_   64
#define L_   256
#define P_   20
#define SD_  8
#define MF_  6
#define H_   256
#define NH_  8
#define HD_  32
#define NL_  3
#define C_   64
#define S_   30
#define N_   321          // 1 + A_ + L_
#define NTOK (B_*N_)      // 2568

// ---------- reduce helpers ----------
__device__ inline float waveSum(float v){
#pragma unroll
  for(int o=32;o;o>>=1) v += __shfl_down(v,o,64);
  return v;
}
__device__ inline float blockMin256(float v, volatile float* red){
#pragma unroll
  for(int o=32;o;o>>=1) v = fminf(v, __shfl_down(v,o,64));
  if((threadIdx.x&63)==0) red[threadIdx.x>>6]=v;
  __syncthreads();
  v = fminf(fminf(red[0],red[1]),fminf(red[2],red[3]));
  __syncthreads();
  return v;
}

// ---------- K0: transpose attention weights ----------
__global__ void k_transpose(const float* __restrict__ attn_in_w,
                            const float* __restrict__ attn_out_w,
                            float* __restrict__ wqT, float* __restrict__ wkT,
                            float* __restrict__ wvT, float* __restrict__ aowT){
  int idx = blockIdx.x*256 + threadIdx.x;   // 0..262143
  int arr = idx >> 16;
  int d   = (idx >> 8) & 255;
  int j   = idx & 255;
  if(arr==0)      wqT[d*H_+j]  = attn_in_w[(size_t)j*H_+d];
  else if(arr==1) wkT[d*H_+j]  = attn_in_w[(size_t)(256+j)*H_+d];
  else if(arr==2) wvT[d*H_+j]  = attn_in_w[(size_t)(512+j)*H_+d];
  else            aowT[d*H_+j] = attn_out_w[(size_t)j*H_+d];
}

// ---------- K1: encode tokens + LayerNorm ----------
__global__ void __launch_bounds__(256) k_encode(
    const float* __restrict__ ego, const float* __restrict__ agents,
    const float* __restrict__ mp,
    const float* __restrict__ w_ego, const float* __restrict__ b_ego,
    const float* __restrict__ w_ag,  const float* __restrict__ b_ag,
    const float* __restrict__ w_map, const float* __restrict__ b_map,
    const float* __restrict__ ln_g,  const float* __restrict__ ln_b,
    float* __restrict__ tokens){
  int b = blockIdx.x / N_;
  int n = blockIdx.x % N_;
  int j = threadIdx.x;
  __shared__ float in_s[SD_];
  __shared__ float red[8];
  const float* W; const float* bias; int D;
  if(n==0){
    if(j<SD_) in_s[j] = ego[(b*10 + 9)*SD_ + j];
    W=w_ego; bias=b_ego; D=SD_;
  } else if(n<=A_){
    int a=n-1;
    if(j<SD_) in_s[j] = agents[(size_t)(b*A_+a)*SD_ + j];
    W=w_ag; bias=b_ag; D=SD_;
  } else {
    int l=n-1-A_;
    if(j<MF_){
      float s=0.f;
      const float* base = mp + (size_t)(b*L_+l)*P_*MF_ + j;
#pragma unroll
      for(int p=0;p<P_;p++) s += base[p*MF_];
      in_s[j] = s * (1.0f/P_);
    }
    W=w_map; bias=b_map; D=MF_;
  }
  __syncthreads();
  float acc = bias[j];
  for(int d=0;d<D;d++) acc += in_s[d]*W[d*H_ + j];
  // LayerNorm over 256 values (1 per thread)
  float s1=acc, s2=acc*acc;
#pragma unroll
  for(int o=32;o;o>>=1){ s1+=__shfl_down(s1,o,64); s2+=__shfl_down(s2,o,64); }
  if((j&63)==0){ red[j>>6]=s1; red[4+(j>>6)]=s2; }
  __syncthreads();
  float m = (red[0]+red[1]+red[2]+red[3]) * (1.0f/H_);
  float v = (red[4]+red[5]+red[6]+red[7]) * (1.0f/H_) - m*m;
  tokens[(size_t)blockIdx.x*H_ + j] = (acc-m)*rsqrtf(v+1e-5f)*ln_g[j] + ln_b[j];
}

// ---------- K2: K/V projection, 8 tokens per block ----------
__global__ void __launch_bounds__(256) k_kv(
    const float* __restrict__ tokens,
    const float* __restrict__ wkT, const float* __restrict__ wvT,
    const float* __restrict__ attn_in_b,
    float* __restrict__ K, float* __restrict__ V){
  int base = blockIdx.x * 8;   // 321 blocks * 8 = 2568 tokens exactly
  int j = threadIdx.x;
  __shared__ float tok_s[8][H_];
#pragma unroll
  for(int t=0;t<8;t++) tok_s[t][j] = tokens[(size_t)(base+t)*H_ + j];
  __syncthreads();
  float bk = attn_in_b[256+j], bv = attn_in_b[512+j];
  float aK[8], aV[8];
#pragma unroll
  for(int t=0;t<8;t++){ aK[t]=bk; aV[t]=bv; }
  for(int d=0;d<H_;d++){
    float wk = wkT[d*H_+j], wv = wvT[d*H_+j];
#pragma unroll
    for(int t=0;t<8;t++){ float x=tok_s[t][d]; aK[t]+=x*wk; aV[t]+=x*wv; }
  }
#pragma unroll
  for(int t=0;t<8;t++){
    K[(size_t)(base+t)*H_+j]=aK[t];
    V[(size_t)(base+t)*H_+j]=aV[t];
  }
}

// ---------- K3: 3-layer fusion (attn + MLP + LN), one block per batch ----------
__global__ void __launch_bounds__(256) k_fused(
    const float* __restrict__ tokens, const float* __restrict__ K, const float* __restrict__ V,
    const float* __restrict__ wqT, const float* __restrict__ aowT,
    const float* __restrict__ attn_in_b, const float* __restrict__ attn_out_b,
    const float* __restrict__ mlp_w1, const float* __restrict__ mlp_b1,
    const float* __restrict__ mlp_w2, const float* __restrict__ mlp_b2,
    const float* __restrict__ pl_g, const float* __restrict__ pl_b,
    float* __restrict__ fused_out){
  int b = blockIdx.x;
  int j = threadIdx.x;
  __shared__ float fused_s[H_];
  __shared__ float q_s[H_];            // also reused for "attended"
  __shared__ float att_s[NH_*N_];
  __shared__ float h1_s[2*H_];
  __shared__ float red[8];
  fused_s[j] = tokens[(size_t)(b*N_)*H_ + j];   // ego token (n==0) post-LN
  __syncthreads();
  for(int i=0;i<NL_;i++){
    // --- Q projection ---
    float q = attn_in_b[j];
    for(int d=0;d<H_;d++) q += fused_s[d]*wqT[d*H_+j];
    q_s[j]=q;
    __syncthreads();
    // --- scores Q.K / sqrt(hd) ---
    for(int idx=j; idx<NH_*N_; idx+=H_){
      int h = idx / N_, n = idx - h*N_;
      const float* Kp = K + (size_t)(b*N_+n)*H_ + h*HD_;
      const float* Qp = q_s + h*HD_;
      float s=0.f;
#pragma unroll
      for(int d=0;d<HD_;d++) s += Qp[d]*Kp[d];
      att_s[idx] = s * 0.17677669529663687f;   // 1/sqrt(32)
    }
    __syncthreads();
    // --- softmax per head (32-lane groups) ---
    {
      int h = j>>5, lane = j&31;
      float mx = -3.0e38f;
      for(int n=lane;n<N_;n+=32) mx = fmaxf(mx, att_s[h*N_+n]);
#pragma unroll
      for(int o=16;o;o>>=1) mx = fmaxf(mx, __shfl_xor(mx,o,32));
      float sm=0.f;
      for(int n=lane;n<N_;n+=32){ float e=expf(att_s[h*N_+n]-mx); att_s[h*N_+n]=e; sm+=e; }
#pragma unroll
      for(int o=16;o;o>>=1) sm += __shfl_xor(sm,o,32);
      float inv = 1.0f/sm;
      for(int n=lane;n<N_;n+=32) att_s[h*N_+n]*=inv;
    }
    __syncthreads();
    // --- attended = att @ V ---
    {
      int h = j>>5;
      float acc=0.f;
      const float* Vp = V + (size_t)(b*N_)*H_ + j;
      const float* ap = att_s + h*N_;
      for(int n=0;n<N_;n++) acc += ap[n]*Vp[(size_t)n*H_];
      __syncthreads();        // everyone done reading q_s from score stage? (done at softmax sync) safe anyway
      q_s[j] = acc;           // reuse as attended
    }
    __syncthreads();
    // --- output projection ---
    float o = attn_out_b[j];
    for(int d=0;d<H_;d++) o += q_s[d]*aowT[d*H_+j];
    // --- MLP layer 1 + exact GELU ---
    const float* w1 = mlp_w1 + (size_t)i*H_*2*H_;
    const float* b1 = mlp_b1 + i*2*H_;
    for(int k=j;k<2*H_;k+=H_){
      float a = b1[k];
      for(int d=0;d<H_;d++) a += fused_s[d]*w1[(size_t)d*2*H_ + k];
      h1_s[k] = a*0.5f*(1.0f+erff(a*0.70710678118654752f));
    }
    __syncthreads();
    // --- MLP layer 2 ---
    const float* w2 = mlp_w2 + (size_t)i*2*H_*H_;
    float h2 = mlp_b2[i*H_ + j];
    for(int k=0;k<2*H_;k++) h2 += h1_s[k]*w2[(size_t)k*H_ + j];
    // --- residual + LN ---
    float x = fused_s[j] + o + h2;
    float s1=x, s2=x*x;
#pragma unroll
    for(int off=32;off;off>>=1){ s1+=__shfl_down(s1,off,64); s2+=__shfl_down(s2,off,64); }
    if((j&63)==0){ red[j>>6]=s1; red[4+(j>>6)]=s2; }
    __syncthreads();
    float m = (red[0]+red[1]+red[2]+red[3])*(1.0f/H_);
    float v = (red[4]+red[5]+red[6]+red[7])*(1.0f/H_) - m*m;
    float y = (x-m)*rsqrtf(v+1e-5f)*pl_g[j] + pl_b[j];
    __syncthreads();
    fused_s[j] = y;
    __syncthreads();
  }
  fused_out[b*H_ + j] = fused_s[j];
}

// ---------- K4: trajectory decode + logits, one block per (b,c) ----------
__global__ void __launch_bounds__(64) k_decode(
    const float* __restrict__ fused, const float* __restrict__ traj_w,
    const float* __restrict__ traj_b, const float* __restrict__ score_w,
    const float* __restrict__ score_b, const float* __restrict__ ego,
    float* __restrict__ o_traj, float* __restrict__ o_logits){
  int b = blockIdx.x >> 6, c = blockIdx.x & 63;
  int t = threadIdx.x;
  __shared__ float fs[H_];
  __shared__ float ds[60];
  for(int d=t; d<H_; d+=64) fs[d] = fused[b*H_ + d];
  __syncthreads();
  if(t<60){
    int col = c*60 + t;
    float a = traj_b[col];
    for(int d=0;d<H_;d++) a += fs[d]*traj_w[(size_t)d*3840 + col];
    ds[t] = tanhf(a)*1.5f;   // MAX_STEP = 1.5
  }
  float lp = 0.f;
  for(int d=t; d<H_; d+=64) lp += fs[d]*score_w[d*64 + c];
  lp = waveSum(lp);
  if(t==0) o_logits[b*64+c] = lp + score_b[c];
  __syncthreads();
  if(t<2){
    float x = ego[(b*10+9)*SD_ + t];   // start_xy
    float* op = o_traj + (size_t)(b*64+c)*60 + t;
    for(int s=0;s<S_;s++){ x += ds[s*2+t]; op[s*2] = x; }
  }
}

// ---------- K5: softmax scores + lane direction, one block per batch ----------
__global__ void __launch_bounds__(64) k_scores_ldir(
    const float* __restrict__ logits, const float* __restrict__ mp,
    float* __restrict__ scores, float* __restrict__ ldir){
  int b = blockIdx.x; int t = threadIdx.x;
  float l = logits[b*64+t];
  float mx = l;
#pragma unroll
  for(int o=32;o;o>>=1) mx = fmaxf(mx, __shfl_xor(mx,o,64));
  float e = expf(l-mx);
  float sm = e;
#pragma unroll
  for(int o=32;o;o>>=1) sm += __shfl_xor(sm,o,64);
  scores[b*64+t] = e/sm;
  float dx=0.f, dy=0.f;
  for(int l2=t;l2<L_;l2+=64){
    const float* p0 = mp + (size_t)(b*L_+l2)*P_*MF_;
    dx += p0[19*MF_+0]-p0[0];
    dy += p0[19*MF_+1]-p0[1];
  }
#pragma unroll
  for(int o=32;o;o>>=1){ dx+=__shfl_xor(dx,o,64); dy+=__shfl_xor(dy,o,64); }
  if(t==0){
    dx *= (1.0f/L_); dy *= (1.0f/L_);
    float nm = fmaxf(sqrtf(dx*dx+dy*dy), 1e-6f);
    ldir[b*2]=dx/nm; ldir[b*2+1]=dy/nm;
  }
}

// ---------- K6: constraints, one block per (b,c) ----------
__global__ void __launch_bounds__(256) k_constraints(
    const float* __restrict__ o_traj, const float* __restrict__ agents,
    const float* __restrict__ mp, const float* __restrict__ ldir,
    float* __restrict__ o_mind, float* __restrict__ o_laned,
    float* __restrict__ o_align, float* __restrict__ o_cost,
    float* __restrict__ valid){
  int b = blockIdx.x >> 6, c = blockIdx.x & 63;
  int t = threadIdx.x;
  __shared__ float ts[60];
  __shared__ float as_[A_*2];
  __shared__ float red[4];
  __shared__ int bad;
  if(t<60) ts[t] = o_traj[(size_t)(b*64+c)*60 + t];
  if(t>=64 && t<192){ int q=t-64; as_[q] = agents[(size_t)(b*A_ + (q>>1))*SD_ + (q&1)]; }
  if(t==0) bad=0;
  __syncthreads();
  // feasibility
  if(t<29){
    float dx = ts[2*t+2]-ts[2*t], dy = ts[2*t+3]-ts[2*t+1];
    if((dx*dx+dy*dy)*100.0f > 225.0f) bad=1;      // |vel| > 15
  }
  if(t<28){
    float x0=ts[2*t],y0=ts[2*t+1],x1=ts[2*t+2],y1=ts[2*t+3],x2=ts[2*t+4],y2=ts[2*t+5];
    float ddx = x2-2.f*x1+x0, ddy = y2-2.f*y1+y0;
    if((ddx*ddx+ddy*ddy)*10000.0f > 25.0f) bad=1; // |acc| > 5
    float d1x=x1-x0, d1y=y1-y0;
    float cross = d1x*ddy - d1y*ddx;
    float n2 = d1x*d1x+d1y*d1y;
    float n3 = fmaxf(n2*sqrtf(n2), 1e-6f);
    if(fabsf(cross) > 0.3f*n3) bad=1;             // curv > 0.3
  }
  // min agent distance (30*64 pairs)
  float md2 = 3.0e38f;
  for(int idx=t; idx<S_*A_; idx+=256){
    int s = idx>>6, a = idx&63;
    float dx = ts[2*s]-as_[2*a], dy = ts[2*s+1]-as_[2*a+1];
    md2 = fminf(md2, dx*dx+dy*dy);
  }
  // lane distance: 20 points/thread in registers, 30 traj points broadcast from LDS
  float lx[20], ly[20];
#pragma unroll
  for(int k=0;k<20;k++){
    int i = t + k*256;   // 5120 = 20*256 exactly
    const float* p = mp + (size_t)(b*5120 + i)*MF_;
    lx[k]=p[0]; ly[k]=p[1];
  }
  float ld2 = 3.0e38f;
  for(int s=0;s<S_;s++){
    float tx=ts[2*s], ty=ts[2*s+1];
#pragma unroll
    for(int k=0;k<20;k++){
      float dx=tx-lx[k], dy=ty-ly[k];
      ld2 = fminf(ld2, dx*dx+dy*dy);
    }
  }
  __syncthreads();
  md2 = blockMin256(md2, red);
  ld2 = blockMin256(ld2, red);
  if(t==0){
    float md = sqrtf(md2), ld = sqrtf(ld2);
    float tdx = ts[58]-ts[0], tdy = ts[59]-ts[1];
    float nm = fmaxf(sqrtf(tdx*tdx+tdy*tdy), 1e-6f);
    tdx/=nm; tdy/=nm;
    float al = tdx*ldir[b*2] + tdy*ldir[b*2+1];
    int ok = (!bad) && (md>=1.5f) && (ld<=4.5f) && (al>=0.0f);
    int oi = b*64+c;
    o_mind[oi]=md; o_laned[oi]=ld; o_align[oi]=al;
    o_cost[oi] = fmaxf(1.5f-md,0.0f) + 0.1f*ld + 0.5f*fmaxf(1.0f-al,0.0f);
    valid[oi] = ok ? 1.0f : 0.0f;
  }
}

// ---------- K7: selection, one block (wave) per batch ----------
__global__ void __launch_bounds__(64) k_select(
    const float* __restrict__ scores, const float* __restrict__ valid,
    const float* __restrict__ o_traj,
    float* __restrict__ o_selidx, float* __restrict__ o_seltraj){
  int b = blockIdx.x; int t = threadIdx.x;
  float sc = scores[b*64+t];
  bool v = valid[b*64+t] > 0.5f;
  unsigned long long bal = __ballot(v);
  float sv = v ? sc : -1.0f;
  float v1=sv; int i1=t;   // argmax(safe_scores), first occurrence
  float v2=sc; int i2=t;   // argmax(scores), first occurrence
#pragma unroll
  for(int o=32;o;o>>=1){
    float ov=__shfl_down(v1,o,64); int oi=__shfl_down(i1,o,64);
    if(ov>v1 || (ov==v1 && oi<i1)){ v1=ov; i1=oi; }
    ov=__shfl_down(v2,o,64); oi=__shfl_down(i2,o,64);
    if(ov>v2 || (ov==v2 && oi<i2)){ v2=ov; i2=oi; }
  }
  int sel = (bal!=0ULL) ? i1 : i2;
  sel = __shfl(sel, 0, 64);
  if(t==0) o_selidx[b] = (float)sel;
  if(t<60) o_seltraj[b*60+t] = o_traj[(size_t)(b*64+sel)*60 + t];
}

// ---------- host launch ----------
extern "C" void kernel_launch(void* const* d_in, const int* in_sizes, int n_in,
                              void* d_out, int out_size, void* d_ws, size_t ws_size,
                              hipStream_t stream) {
  const float* ego        = (const float*)d_in[0];
  const float* agents     = (const float*)d_in[1];
  const float* mp         = (const float*)d_in[2];
  const float* enc_ego_w  = (const float*)d_in[3];
  const float* enc_ego_b  = (const float*)d_in[4];
  const float* enc_ag_w   = (const float*)d_in[5];
  const float* enc_ag_b   = (const float*)d_in[6];
  const float* enc_map_w  = (const float*)d_in[7];
  const float* enc_map_b  = (const float*)d_in[8];
  const float* enc_ln_g   = (const float*)d_in[9];
  const float* enc_ln_b   = (const float*)d_in[10];
  const float* attn_in_w  = (const float*)d_in[11];
  const float* attn_in_b  = (const float*)d_in[12];
  const float* attn_out_w = (const float*)d_in[13];
  const float* attn_out_b = (const float*)d_in[14];
  const float* mlp_w1     = (const float*)d_in[15];
  const float* mlp_b1     = (const float*)d_in[16];
  const float* mlp_w2     = (const float*)d_in[17];
  const float* mlp_b2     = (const float*)d_in[18];
  const float* pl_ln_g    = (const float*)d_in[19];
  const float* pl_ln_b    = (const float*)d_in[20];
  const float* traj_w     = (const float*)d_in[21];
  const float* traj_b     = (const float*)d_in[22];
  const float* score_w    = (const float*)d_in[23];
  const float* score_b    = (const float*)d_in[24];

  float* out = (float*)d_out;
  // output layout (floats)
  float* o_traj    = out;            // 30720
  float* o_logits  = out + 30720;    // 512
  float* o_scores  = out + 31232;    // 512
  float* o_selidx  = out + 31744;    // 8
  float* o_seltraj = out + 31752;    // 480
  float* o_mind    = out + 32232;    // 512
  float* o_laned   = out + 32744;    // 512
  float* o_align   = out + 33256;    // 512
  float* o_cost    = out + 33768;    // 512

  float* ws = (float*)d_ws;
  float* tokens = ws;                  // 657408
  float* K      = ws + 657408;         // 657408
  float* V      = ws + 1314816;        // 657408
  float* wqT    = ws + 1972224;        // 65536
  float* wkT    = ws + 2037760;        // 65536
  float* wvT    = ws + 2103296;        // 65536
  float* aowT   = ws + 2168832;        // 65536
  float* fusedv = ws + 2234368;        // 2048
  float* ldir   = ws + 2236416;        // 16
  float* validv = ws + 2236432;        // 512

  k_transpose<<<1024,256,0,stream>>>(attn_in_w, attn_out_w, wqT, wkT, wvT, aowT);
  k_encode<<<NTOK,256,0,stream>>>(ego, agents, mp, enc_ego_w, enc_ego_b,
                                  enc_ag_w, enc_ag_b, enc_map_w, enc_map_b,
                                  enc_ln_g, enc_ln_b, tokens);
  k_kv<<<NTOK/8,256,0,stream>>>(tokens, wkT, wvT, attn_in_b, K, V);
  k_fused<<<B_,256,0,stream>>>(tokens, K, V, wqT, aowT, attn_in_b, attn_out_b,
                               mlp_w1, mlp_b1, mlp_w2, mlp_b2, pl_ln_g, pl_ln_b, fusedv);
  k_decode<<<B_*C_,64,0,stream>>>(fusedv, traj_w, traj_b, score_w, score_b, ego,
                                  o_traj, o_logits);
  k_scores_ldir<<<B_,64,0,stream>>>(o_logits, mp, o_scores, ldir);
  k_constraints<<<B_*C_,256,0,stream>>>(o_traj, agents, mp, ldir,
                                        o_mind, o_laned, o_align, o_cost, validv);
  k_select<<<B_,64,0,stream>>>(o_scores, validv, o_traj, o_selidx, o_seltraj);
}

// Round 2
// 289.474 us; speedup vs baseline: 1.2604x; 1.2604x over previous
//
#include <hip/hip_runtime.h>
#include <math.h>
#include <stddef.h>

// ---------- problem constants ----------
#define B_   8
#define A_   64
#define L_   256
#define P_   20
#define SD_  8
#define MF_  6
#define H_   256
#define NH_  8
#define HD_  32
#define NL_  3
#define C_   64
#define S_   30
#define N_   321          // 1 + A_ + L_
#define NTOK (B_*N_)      // 2568

// ---------- reduce helpers ----------
__device__ inline float waveSum(float v){
#pragma unroll
  for(int o=32;o;o>>=1) v += __shfl_down(v,o,64);
  return v;
}
__device__ inline float blockMin256(float v, volatile float* red){
#pragma unroll
  for(int o=32;o;o>>=1) v = fminf(v, __shfl_down(v,o,64));
  if((threadIdx.x&63)==0) red[threadIdx.x>>6]=v;
  __syncthreads();
  v = fminf(fminf(red[0],red[1]),fminf(red[2],red[3]));
  __syncthreads();
  return v;
}

// ---------- K0: transpose attention weights ----------
__global__ void k_transpose(const float* __restrict__ attn_in_w,
                            const float* __restrict__ attn_out_w,
                            float* __restrict__ wqT, float* __restrict__ wkT,
                            float* __restrict__ wvT, float* __restrict__ aowT){
  int idx = blockIdx.x*256 + threadIdx.x;   // 0..262143
  int arr = idx >> 16;
  int d   = (idx >> 8) & 255;
  int j   = idx & 255;
  if(arr==0)      wqT[d*H_+j]  = attn_in_w[(size_t)j*H_+d];
  else if(arr==1) wkT[d*H_+j]  = attn_in_w[(size_t)(256+j)*H_+d];
  else if(arr==2) wvT[d*H_+j]  = attn_in_w[(size_t)(512+j)*H_+d];
  else            aowT[d*H_+j] = attn_out_w[(size_t)j*H_+d];
}

// ---------- K1: encode tokens + LayerNorm ----------
__global__ void __launch_bounds__(256) k_encode(
    const float* __restrict__ ego, const float* __restrict__ agents,
    const float* __restrict__ mp,
    const float* __restrict__ w_ego, const float* __restrict__ b_ego,
    const float* __restrict__ w_ag,  const float* __restrict__ b_ag,
    const float* __restrict__ w_map, const float* __restrict__ b_map,
    const float* __restrict__ ln_g,  const float* __restrict__ ln_b,
    float* __restrict__ tokens){
  int b = blockIdx.x / N_;
  int n = blockIdx.x % N_;
  int j = threadIdx.x;
  __shared__ float in_s[SD_];
  __shared__ float red[8];
  const float* W; const float* bias; int D;
  if(n==0){
    if(j<SD_) in_s[j] = ego[(b*10 + 9)*SD_ + j];
    W=w_ego; bias=b_ego; D=SD_;
  } else if(n<=A_){
    int a=n-1;
    if(j<SD_) in_s[j] = agents[(size_t)(b*A_+a)*SD_ + j];
    W=w_ag; bias=b_ag; D=SD_;
  } else {
    int l=n-1-A_;
    if(j<MF_){
      float s=0.f;
      const float* base = mp + (size_t)(b*L_+l)*P_*MF_ + j;
#pragma unroll
      for(int p=0;p<P_;p++) s += base[p*MF_];
      in_s[j] = s * (1.0f/P_);
    }
    W=w_map; bias=b_map; D=MF_;
  }
  __syncthreads();
  float acc = bias[j];
  for(int d=0;d<D;d++) acc += in_s[d]*W[d*H_ + j];
  float s1=acc, s2=acc*acc;
#pragma unroll
  for(int o=32;o;o>>=1){ s1+=__shfl_down(s1,o,64); s2+=__shfl_down(s2,o,64); }
  if((j&63)==0){ red[j>>6]=s1; red[4+(j>>6)]=s2; }
  __syncthreads();
  float m = (red[0]+red[1]+red[2]+red[3]) * (1.0f/H_);
  float v = (red[4]+red[5]+red[6]+red[7]) * (1.0f/H_) - m*m;
  tokens[(size_t)blockIdx.x*H_ + j] = (acc-m)*rsqrtf(v+1e-5f)*ln_g[j] + ln_b[j];
}

// ---------- K2: K/V projection, 8 tokens per block ----------
__global__ void __launch_bounds__(256) k_kv(
    const float* __restrict__ tokens,
    const float* __restrict__ wkT, const float* __restrict__ wvT,
    const float* __restrict__ attn_in_b,
    float* __restrict__ K, float* __restrict__ V){
  int base = blockIdx.x * 8;
  int j = threadIdx.x;
  __shared__ float tok_s[8][H_];
#pragma unroll
  for(int t=0;t<8;t++) tok_s[t][j] = tokens[(size_t)(base+t)*H_ + j];
  __syncthreads();
  float bk = attn_in_b[256+j], bv = attn_in_b[512+j];
  float aK[8], aV[8];
#pragma unroll
  for(int t=0;t<8;t++){ aK[t]=bk; aV[t]=bv; }
#pragma unroll 4
  for(int d=0;d<H_;d++){
    float wk = wkT[d*H_+j], wv = wvT[d*H_+j];
#pragma unroll
    for(int t=0;t<8;t++){ float x=tok_s[t][d]; aK[t]+=x*wk; aV[t]+=x*wv; }
  }
#pragma unroll
  for(int t=0;t<8;t++){
    K[(size_t)(base+t)*H_+j]=aK[t];
    V[(size_t)(base+t)*H_+j]=aV[t];
  }
}

// ---------- K3: 3-layer fusion, one 1024-thread block per batch ----------
// Every GEMV is 4-way K-split: output j computed by 4 threads (slices), each
// over 64-128 inputs, partials reduced via LDS. 16 waves/block = 4 waves/SIMD.
__global__ void __launch_bounds__(1024) k_fused(
    const float* __restrict__ tokens, const float* __restrict__ K, const float* __restrict__ V,
    const float* __restrict__ wqT, const float* __restrict__ aowT,
    const float* __restrict__ attn_in_b, const float* __restrict__ attn_out_b,
    const float* __restrict__ mlp_w1, const float* __restrict__ mlp_b1,
    const float* __restrict__ mlp_w2, const float* __restrict__ mlp_b2,
    const float* __restrict__ pl_g, const float* __restrict__ pl_b,
    float* __restrict__ fused_out){
  int b = blockIdx.x;
  int t = threadIdx.x;          // 0..1023
  int j  = t & 255;             // output index for H-wide GEMVs
  int sl = t >> 8;              // slice 0..3
  __shared__ float fused_s[H_];
  __shared__ float vec_s[H_];         // q, then attended
  __shared__ float atn_s[H_];         // attention output (post out-proj)
  __shared__ float part_s[4][H_];     // GEMV partials (also viewed as [2][512])
  __shared__ float att_s[NH_*N_];     // 2568 scores
  __shared__ float h1_s[2*H_];
  __shared__ float red[8];
  if(t < H_) fused_s[t] = tokens[(size_t)(b*N_)*H_ + t];
  __syncthreads();

  for(int i=0;i<NL_;i++){
    // --- Q projection: 4 slices x 64 d ---
    {
      const float* w = wqT + (size_t)(sl*64)*H_ + j;
      float acc = 0.f;
#pragma unroll 16
      for(int d=0;d<64;d++) acc += fused_s[sl*64+d] * w[(size_t)d*H_];
      part_s[sl][j] = acc;
    }
    __syncthreads();
    if(t < H_) vec_s[t] = part_s[0][t]+part_s[1][t]+part_s[2][t]+part_s[3][t] + attn_in_b[t];
    __syncthreads();
    // --- scores Q.K / sqrt(hd) : 2568 dot-32 over 1024 threads ---
    for(int idx=t; idx<NH_*N_; idx+=1024){
      int h = idx / N_, n = idx - h*N_;
      const float4* Kp = (const float4*)(K + (size_t)(b*N_+n)*H_ + h*HD_);
      const float4* Qp = (const float4*)(vec_s + h*HD_);
      float s=0.f;
#pragma unroll
      for(int d4=0; d4<8; d4++){
        float4 kk = Kp[d4], qq = Qp[d4];
        s += kk.x*qq.x + kk.y*qq.y + kk.z*qq.z + kk.w*qq.w;
      }
      att_s[idx] = s * 0.17677669529663687f;
    }
    __syncthreads();
    // --- softmax per head: 8 heads x 64 lanes (threads 0..511) ---
    if(t < 512){
      int h = t>>6, lane = t&63;
      float mx = -3.0e38f;
      for(int n=lane;n<N_;n+=64) mx = fmaxf(mx, att_s[h*N_+n]);
#pragma unroll
      for(int o=32;o;o>>=1) mx = fmaxf(mx, __shfl_xor(mx,o,64));
      float sm=0.f;
      for(int n=lane;n<N_;n+=64){ float e=expf(att_s[h*N_+n]-mx); att_s[h*N_+n]=e; sm+=e; }
#pragma unroll
      for(int o=32;o;o>>=1) sm += __shfl_xor(sm,o,64);
      float inv = 1.0f/sm;
      for(int n=lane;n<N_;n+=64) att_s[h*N_+n]*=inv;
    }
    __syncthreads();
    // --- attended = att @ V : 4 key-slices of ~81 ---
    {
      int n0 = sl*81;
      int n1 = (sl==3) ? N_ : n0+81;
      int h = j>>5;
      const float* Vp = V + (size_t)(b*N_)*H_ + j;
      const float* ap = att_s + h*N_;
      float acc=0.f;
      for(int n=n0;n<n1;n++) acc += ap[n]*Vp[(size_t)n*H_];
      part_s[sl][j] = acc;
    }
    __syncthreads();
    if(t < H_) vec_s[t] = part_s[0][t]+part_s[1][t]+part_s[2][t]+part_s[3][t];
    __syncthreads();
    // --- output projection: 4 slices x 64 d ---
    {
      const float* w = aowT + (size_t)(sl*64)*H_ + j;
      float acc=0.f;
#pragma unroll 16
      for(int d=0;d<64;d++) acc += vec_s[sl*64+d]*w[(size_t)d*H_];
      part_s[sl][j] = acc;
    }
    __syncthreads();
    if(t < H_) atn_s[t] = part_s[0][t]+part_s[1][t]+part_s[2][t]+part_s[3][t] + attn_out_b[t];
    __syncthreads();
    // --- MLP1: 512 outputs, 2 halves x 128 d ---
    {
      int k = t & 511, hf = t >> 9;
      const float* w1 = mlp_w1 + (size_t)i*H_*512 + (size_t)(hf*128)*512 + k;
      float acc=0.f;
#pragma unroll 16
      for(int d=0;d<128;d++) acc += fused_s[hf*128+d]*w1[(size_t)d*512];
      ((float*)part_s)[hf*512 + k] = acc;
    }
    __syncthreads();
    if(t < 512){
      float a = ((float*)part_s)[t] + ((float*)part_s)[512+t] + mlp_b1[i*512+t];
      h1_s[t] = a*0.5f*(1.0f+erff(a*0.70710678118654752f));
    }
    __syncthreads();
    // --- MLP2: 256 outputs, 4 slices x 128 d ---
    {
      const float* w2 = mlp_w2 + (size_t)i*512*H_ + (size_t)(sl*128)*H_ + j;
      float acc=0.f;
#pragma unroll 16
      for(int d=0;d<128;d++) acc += h1_s[sl*128+d]*w2[(size_t)d*H_];
      part_s[sl][j] = acc;
    }
    __syncthreads();
    // --- residual + LN (threads 0..255) ---
    float x = 0.f;
    if(t < H_){
      x = fused_s[t] + atn_s[t]
        + part_s[0][t]+part_s[1][t]+part_s[2][t]+part_s[3][t] + mlp_b2[i*H_+t];
      float s1=x, s2=x*x;
#pragma unroll
      for(int o=32;o;o>>=1){ s1+=__shfl_down(s1,o,64); s2+=__shfl_down(s2,o,64); }
      if((t&63)==0){ red[t>>6]=s1; red[4+(t>>6)]=s2; }
    }
    __syncthreads();
    if(t < H_){
      float m = (red[0]+red[1]+red[2]+red[3])*(1.0f/H_);
      float v = (red[4]+red[5]+red[6]+red[7])*(1.0f/H_) - m*m;
      fused_s[t] = (x-m)*rsqrtf(v+1e-5f)*pl_g[t] + pl_b[t];
    }
    __syncthreads();
  }
  if(t < H_) fused_out[b*H_ + t] = fused_s[t];
}

// ---------- K4: trajectory decode + logits, 256 threads per (b,c) ----------
__global__ void __launch_bounds__(256) k_decode(
    const float* __restrict__ fused, const float* __restrict__ traj_w,
    const float* __restrict__ traj_b, const float* __restrict__ score_w,
    const float* __restrict__ score_b, const float* __restrict__ ego,
    float* __restrict__ o_traj, float* __restrict__ o_logits){
  int b = blockIdx.x >> 6, c = blockIdx.x & 63;
  int t = threadIdx.x;
  int j = t & 63, sl = t >> 6;      // 4 slices x 64 d
  __shared__ float fs[H_];
  __shared__ float part[4][64];
  __shared__ float ds[60];
  __shared__ float redsc[4];
  fs[t] = fused[b*H_ + t];
  __syncthreads();
  if(j < 60){
    int col = c*60 + j;
    const float* w = traj_w + (size_t)(sl*64)*3840 + col;
    float acc=0.f;
#pragma unroll 16
    for(int d=0;d<64;d++) acc += fs[sl*64+d]*w[(size_t)d*3840];
    part[sl][j] = acc;
  }
  // logits: each thread one d
  float lp = fs[t]*score_w[t*64 + c];
  lp = waveSum(lp);
  if((t&63)==0) redsc[t>>6]=lp;
  __syncthreads();
  if(t < 60){
    float a = part[0][t]+part[1][t]+part[2][t]+part[3][t] + traj_b[c*60+t];
    ds[t] = tanhf(a)*1.5f;   // MAX_STEP
  }
  if(t==0) o_logits[b*64+c] = redsc[0]+redsc[1]+redsc[2]+redsc[3] + score_b[c];
  __syncthreads();
  if(t<2){
    float x = ego[(b*10+9)*SD_ + t];
    float* op = o_traj + (size_t)(b*64+c)*60 + t;
    for(int s=0;s<S_;s++){ x += ds[s*2+t]; op[s*2] = x; }
  }
}

// ---------- K5: softmax scores + lane direction ----------
__global__ void __launch_bounds__(64) k_scores_ldir(
    const float* __restrict__ logits, const float* __restrict__ mp,
    float* __restrict__ scores, float* __restrict__ ldir){
  int b = blockIdx.x; int t = threadIdx.x;
  float l = logits[b*64+t];
  float mx = l;
#pragma unroll
  for(int o=32;o;o>>=1) mx = fmaxf(mx, __shfl_xor(mx,o,64));
  float e = expf(l-mx);
  float sm = e;
#pragma unroll
  for(int o=32;o;o>>=1) sm += __shfl_xor(sm,o,64);
  scores[b*64+t] = e/sm;
  float dx=0.f, dy=0.f;
  for(int l2=t;l2<L_;l2+=64){
    const float* p0 = mp + (size_t)(b*L_+l2)*P_*MF_;
    dx += p0[19*MF_+0]-p0[0];
    dy += p0[19*MF_+1]-p0[1];
  }
#pragma unroll
  for(int o=32;o;o>>=1){ dx+=__shfl_xor(dx,o,64); dy+=__shfl_xor(dy,o,64); }
  if(t==0){
    dx *= (1.0f/L_); dy *= (1.0f/L_);
    float nm = fmaxf(sqrtf(dx*dx+dy*dy), 1e-6f);
    ldir[b*2]=dx/nm; ldir[b*2+1]=dy/nm;
  }
}

// ---------- K6: constraints, one block per (b,c) ----------
__global__ void __launch_bounds__(256) k_constraints(
    const float* __restrict__ o_traj, const float* __restrict__ agents,
    const float* __restrict__ mp, const float* __restrict__ ldir,
    float* __restrict__ o_mind, float* __restrict__ o_laned,
    float* __restrict__ o_align, float* __restrict__ o_cost,
    float* __restrict__ valid){
  int b = blockIdx.x >> 6, c = blockIdx.x & 63;
  int t = threadIdx.x;
  __shared__ float ts[60];
  __shared__ float as_[A_*2];
  __shared__ float red[4];
  __shared__ int bad;
  if(t<60) ts[t] = o_traj[(size_t)(b*64+c)*60 + t];
  if(t>=64 && t<192){ int q=t-64; as_[q] = agents[(size_t)(b*A_ + (q>>1))*SD_ + (q&1)]; }
  if(t==0) bad=0;
  __syncthreads();
  if(t<29){
    float dx = ts[2*t+2]-ts[2*t], dy = ts[2*t+3]-ts[2*t+1];
    if((dx*dx+dy*dy)*100.0f > 225.0f) bad=1;      // |vel| > 15
  }
  if(t<28){
    float x0=ts[2*t],y0=ts[2*t+1],x1=ts[2*t+2],y1=ts[2*t+3],x2=ts[2*t+4],y2=ts[2*t+5];
    float ddx = x2-2.f*x1+x0, ddy = y2-2.f*y1+y0;
    if((ddx*ddx+ddy*ddy)*10000.0f > 25.0f) bad=1; // |acc| > 5
    float d1x=x1-x0, d1y=y1-y0;
    float cross = d1x*ddy - d1y*ddx;
    float n2 = d1x*d1x+d1y*d1y;
    float n3 = fmaxf(n2*sqrtf(n2), 1e-6f);
    if(fabsf(cross) > 0.3f*n3) bad=1;             // curv > 0.3
  }
  float md2 = 3.0e38f;
  for(int idx=t; idx<S_*A_; idx+=256){
    int s = idx>>6, a = idx&63;
    float dx = ts[2*s]-as_[2*a], dy = ts[2*s+1]-as_[2*a+1];
    md2 = fminf(md2, dx*dx+dy*dy);
  }
  float lx[20], ly[20];
#pragma unroll
  for(int k=0;k<20;k++){
    int i = t + k*256;
    const float* p = mp + (size_t)(b*5120 + i)*MF_;
    lx[k]=p[0]; ly[k]=p[1];
  }
  float ld2 = 3.0e38f;
  for(int s=0;s<S_;s++){
    float tx=ts[2*s], ty=ts[2*s+1];
#pragma unroll
    for(int k=0;k<20;k++){
      float dx=tx-lx[k], dy=ty-ly[k];
      ld2 = fminf(ld2, dx*dx+dy*dy);
    }
  }
  __syncthreads();
  md2 = blockMin256(md2, red);
  ld2 = blockMin256(ld2, red);
  if(t==0){
    float md = sqrtf(md2), ld = sqrtf(ld2);
    float tdx = ts[58]-ts[0], tdy = ts[59]-ts[1];
    float nm = fmaxf(sqrtf(tdx*tdx+tdy*tdy), 1e-6f);
    tdx/=nm; tdy/=nm;
    float al = tdx*ldir[b*2] + tdy*ldir[b*2+1];
    int ok = (!bad) && (md>=1.5f) && (ld<=4.5f) && (al>=0.0f);
    int oi = b*64+c;
    o_mind[oi]=md; o_laned[oi]=ld; o_align[oi]=al;
    o_cost[oi] = fmaxf(1.5f-md,0.0f) + 0.1f*ld + 0.5f*fmaxf(1.0f-al,0.0f);
    valid[oi] = ok ? 1.0f : 0.0f;
  }
}

// ---------- K7: selection ----------
__global__ void __launch_bounds__(64) k_select(
    const float* __restrict__ scores, const float* __restrict__ valid,
    const float* __restrict__ o_traj,
    float* __restrict__ o_selidx, float* __restrict__ o_seltraj){
  int b = blockIdx.x; int t = threadIdx.x;
  float sc = scores[b*64+t];
  bool v = valid[b*64+t] > 0.5f;
  unsigned long long bal = __ballot(v);
  float sv = v ? sc : -1.0f;
  float v1=sv; int i1=t;
  float v2=sc; int i2=t;
#pragma unroll
  for(int o=32;o;o>>=1){
    float ov=__shfl_down(v1,o,64); int oi=__shfl_down(i1,o,64);
    if(ov>v1 || (ov==v1 && oi<i1)){ v1=ov; i1=oi; }
    ov=__shfl_down(v2,o,64); oi=__shfl_down(i2,o,64);
    if(ov>v2 || (ov==v2 && oi<i2)){ v2=ov; i2=oi; }
  }
  int sel = (bal!=0ULL) ? i1 : i2;
  sel = __shfl(sel, 0, 64);
  if(t==0) o_selidx[b] = (float)sel;
  if(t<60) o_seltraj[b*60+t] = o_traj[(size_t)(b*64+sel)*60 + t];
}

// ---------- host launch ----------
extern "C" void kernel_launch(void* const* d_in, const int* in_sizes, int n_in,
                              void* d_out, int out_size, void* d_ws, size_t ws_size,
                              hipStream_t stream) {
  const float* ego        = (const float*)d_in[0];
  const float* agents     = (const float*)d_in[1];
  const float* mp         = (const float*)d_in[2];
  const float* enc_ego_w  = (const float*)d_in[3];
  const float* enc_ego_b  = (const float*)d_in[4];
  const float* enc_ag_w   = (const float*)d_in[5];
  const float* enc_ag_b   = (const float*)d_in[6];
  const float* enc_map_w  = (const float*)d_in[7];
  const float* enc_map_b  = (const float*)d_in[8];
  const float* enc_ln_g   = (const float*)d_in[9];
  const float* enc_ln_b   = (const float*)d_in[10];
  const float* attn_in_w  = (const float*)d_in[11];
  const float* attn_in_b  = (const float*)d_in[12];
  const float* attn_out_w = (const float*)d_in[13];
  const float* attn_out_b = (const float*)d_in[14];
  const float* mlp_w1     = (const float*)d_in[15];
  const float* mlp_b1     = (const float*)d_in[16];
  const float* mlp_w2     = (const float*)d_in[17];
  const float* mlp_b2     = (const float*)d_in[18];
  const float* pl_ln_g    = (const float*)d_in[19];
  const float* pl_ln_b    = (const float*)d_in[20];
  const float* traj_w     = (const float*)d_in[21];
  const float* traj_b     = (const float*)d_in[22];
  const float* score_w    = (const float*)d_in[23];
  const float* score_b    = (const float*)d_in[24];

  float* out = (float*)d_out;
  float* o_traj    = out;            // 30720
  float* o_logits  = out + 30720;    // 512
  float* o_scores  = out + 31232;    // 512
  float* o_selidx  = out + 31744;    // 8
  float* o_seltraj = out + 31752;    // 480
  float* o_mind    = out + 32232;    // 512
  float* o_laned   = out + 32744;    // 512
  float* o_align   = out + 33256;    // 512
  float* o_cost    = out + 33768;    // 512

  float* ws = (float*)d_ws;
  float* tokens = ws;                  // 657408
  float* K      = ws + 657408;         // 657408
  float* V      = ws + 1314816;        // 657408
  float* wqT    = ws + 1972224;        // 65536
  float* wkT    = ws + 2037760;        // 65536
  float* wvT    = ws + 2103296;        // 65536
  float* aowT   = ws + 2168832;        // 65536
  float* fusedv = ws + 2234368;        // 2048
  float* ldir   = ws + 2236416;        // 16
  float* validv = ws + 2236432;        // 512

  k_transpose<<<1024,256,0,stream>>>(attn_in_w, attn_out_w, wqT, wkT, wvT, aowT);
  k_encode<<<NTOK,256,0,stream>>>(ego, agents, mp, enc_ego_w, enc_ego_b,
                                  enc_ag_w, enc_ag_b, enc_map_w, enc_map_b,
                                  enc_ln_g, enc_ln_b, tokens);
  k_kv<<<NTOK/8,256,0,stream>>>(tokens, wkT, wvT, attn_in_b, K, V);
  k_fused<<<B_,1024,0,stream>>>(tokens, K, V, wqT, aowT, attn_in_b, attn_out_b,
                                mlp_w1, mlp_b1, mlp_w2, mlp_b2, pl_ln_g, pl_ln_b, fusedv);
  k_decode<<<B_*C_,256,0,stream>>>(fusedv, traj_w, traj_b, score_w, score_b, ego,
                                   o_traj, o_logits);
  k_scores_ldir<<<B_,64,0,stream>>>(o_logits, mp, o_scores, ldir);
  k_constraints<<<B_*C_,256,0,stream>>>(o_traj, agents, mp, ldir,
                                        o_mind, o_laned, o_align, o_cost, validv);
  k_select<<<B_,64,0,stream>>>(o_scores, validv, o_traj, o_selidx, o_seltraj);
}